// Round 14
// baseline (196.763 us; speedup 1.0000x reference)
//
#include <hip/hip_runtime.h>
#include <hip/hip_bf16.h>
#include <stdint.h>

typedef __hip_bfloat16 bf16;
typedef float f32x4 __attribute__((ext_vector_type(4)));
typedef short bf16x8 __attribute__((ext_vector_type(8)));

#define NB 16384
#define NA 16
#define ND 512
#define NH 512
#define TR 80

// workspace layout (bytes)
#define W1S_OFF 0u
#define W2S_OFF 8388608u
#define PERM_OFF 16777216u
#define META_OFF 16842752u
// meta ints: [0..15]=cnt, [16..31]=off, [32]=permflag, [33..40]=jobcnt[xcd]

__device__ __forceinline__ unsigned short f2b(float x) {
  unsigned int b = __float_as_uint(x);
  return (unsigned short)((b + 0x7FFFu + ((b >> 16) & 1u)) >> 16);  // RNE
}

// ---------------- fused persistent kernel: meta + weight transpose + grouped MLP ----------
// Grid 256 = 1 block/CU (87KB LDS), all co-resident -> spin-wait safe.
// Block 0: meta+perm -> fence -> permflag. Blocks 1..255: transpose own XCD's 4 weight
// matrices (XCD-pinned; consumers same-XCD) -> fence -> jobcnt[xcd]. Then all: spin perm,
// stage X, spin jobcnt==256, run the 16-wave MLP (identical to round-12 k_main).
// Weight layout per action: blob[(h>>4)*16 + (k>>5)] of 1KB; byte =
// ((k>>3)&3)*256 + (h&15)*16 + (k&7)*2.
__global__ __launch_bounds__(1024, 4) void k_fused(
    const float* __restrict__ state, const float* __restrict__ W1,
    const float* __restrict__ b1, const float* __restrict__ W2,
    const float* __restrict__ b2, const float* __restrict__ W3,
    const float* __restrict__ b3, const int* __restrict__ act,
    bf16* __restrict__ W1s, bf16* __restrict__ W2s,
    int* __restrict__ perm, int* __restrict__ meta, float* __restrict__ out) {
  extern __shared__ char smem[];
  char* Xs = smem;                       // 80KB scratch: transpose tiles / hist / X / h1
  float* outbuf = (float*)(smem + 81920);

  int bid = blockIdx.x;
  int tid = threadIdx.x;
  int xcd = bid & 7, slot = bid >> 3;

  if (bid == 0) {
    // ---- meta: hist + wave-scan + scatter (256 threads; block-wide barriers) ----
    int* hist = (int*)Xs;                // [16][256]
    int* off16 = (int*)(Xs + 16384);
    int t = tid & 255;
    bool mt = tid < 256;
    int lane = t & 63, wv = t >> 6;
    if (mt) {
#pragma unroll
      for (int i = 0; i < 16; ++i) hist[i * 256 + t] = 0;
    }
    __syncthreads();
    if (mt) {
      for (int j = 0; j < 64; ++j) {
        int a = act[t + (j << 8)] & 15;
        hist[a * 256 + t]++;
      }
    }
    __syncthreads();
    if (mt) {
      for (int q = 0; q < 4; ++q) {
        int a = (wv << 2) + q;
        int base = lane << 2;
        int v0 = hist[a * 256 + base + 0];
        int v1 = hist[a * 256 + base + 1];
        int v2 = hist[a * 256 + base + 2];
        int v3 = hist[a * 256 + base + 3];
        int s = v0 + v1 + v2 + v3;
        int incl = s;
#pragma unroll
        for (int d = 1; d < 64; d <<= 1) {
          int y = __shfl_up(incl, d);
          if (lane >= d) incl += y;
        }
        int excl = incl - s;
        hist[a * 256 + base + 0] = excl;
        hist[a * 256 + base + 1] = excl + v0;
        hist[a * 256 + base + 2] = excl + v0 + v1;
        hist[a * 256 + base + 3] = excl + v0 + v1 + v2;
        if (lane == 63) off16[a] = incl;
      }
    }
    __syncthreads();
    if (tid == 0) {
      int o = 0;
      for (int aa = 0; aa < 16; ++aa) {
        int c = off16[aa];
        meta[aa] = c;
        meta[16 + aa] = o;
        off16[aa] = o;
        o += c;
      }
    }
    __syncthreads();
    if (mt) {
      for (int j = 0; j < 64; ++j) {
        int idx = t + (j << 8);
        int a = act[idx] & 15;
        int pos = off16[a] + hist[a * 256 + t]++;
        perm[pos] = idx;
      }
    }
    __syncthreads();
    if (tid == 0) {
      __threadfence();  // agent fence: flush meta/perm past XCD0 L2
      atomicAdd(&meta[32], 1);
    }
  } else {
    // ---- transpose duty: 4 tiles/round in LDS (group g = tid>>8 handles one tile) ----
    int grp = tid >> 8, t2 = tid & 255;
    float* tile = (float*)(Xs + grp * 16640);  // [64][65] f32
    int c = slot - 1;                          // xcd0 job class (slot>=1 here when xcd==0)
    int rounds = (xcd != 0) ? 2 : 3;
    for (int r = 0; r < rounds; ++r) {
      int m = grp + (r << 2);
      int j = (xcd != 0) ? (slot + (m << 5)) : (c + 31 * m);
      bool valid = (xcd != 0) ? true : (j < 256);
      int mi = j >> 6;                         // 0..3
      int mat = (mi < 2) ? ((xcd << 1) + mi) : (NA + (xcd << 1) + (mi - 2));
      const float* src = (mat < NA) ? (W1 + (size_t)mat * (ND * NH))
                                    : (W2 + (size_t)(mat - NA) * (ND * NH));
      char* dstb = (mat < NA) ? ((char*)W1s + ((size_t)mat << 19))
                              : ((char*)W2s + ((size_t)(mat - NA) << 19));
      int tl = j & 63;
      int td = tl >> 3, th = tl & 7;
      if (valid) {
        int rr = t2 >> 2, c0 = (t2 & 3) << 4;
        const float* sp = src + (size_t)(td * 64 + rr) * NH + th * 64 + c0;
        float4 v0 = ((const float4*)sp)[0];
        float4 v1 = ((const float4*)sp)[1];
        float4 v2 = ((const float4*)sp)[2];
        float4 v3 = ((const float4*)sp)[3];
        float* trp = &tile[rr * 65 + c0];
        trp[0] = v0.x; trp[1] = v0.y; trp[2] = v0.z; trp[3] = v0.w;
        trp[4] = v1.x; trp[5] = v1.y; trp[6] = v1.z; trp[7] = v1.w;
        trp[8] = v2.x; trp[9] = v2.y; trp[10] = v2.z; trp[11] = v2.w;
        trp[12] = v3.x; trp[13] = v3.y; trp[14] = v3.z; trp[15] = v3.w;
      }
      __syncthreads();
      if (valid) {
        int wv = t2 >> 6, l = t2 & 63;
        int l15b = l & 15, l4b = l >> 4;
#pragma unroll
        for (int kc = 0; kc < 2; ++kc) {
          union { unsigned short us[8]; uint4 q; } u;
#pragma unroll
          for (int i = 0; i < 8; ++i)
            u.us[i] = f2b(tile[(kc * 32 + l4b * 8 + i) * 65 + wv * 16 + l15b]);
          int hb = th * 4 + wv;
          int kb = td * 2 + kc;
          *(uint4*)(dstb + ((size_t)(hb * 16 + kb) << 10) + (l << 4)) = u.q;
        }
      }
      __syncthreads();
    }
    if (tid == 0) {
      int nj;
      if (xcd != 0) {
        nj = 8;
      } else {
        nj = 0;
        for (int m = 0; m < 12; ++m) nj += (c + 31 * m < 256) ? 1 : 0;
      }
      __threadfence();  // flush weight blobs to L2/coherence point
      atomicAdd(&meta[33 + xcd], nj);
    }
  }

  // ---- wait for perm/meta ----
  if (tid == 0) {
    while (__hip_atomic_load(&meta[32], __ATOMIC_RELAXED, __HIP_MEMORY_SCOPE_AGENT) < 1) {}
  }
  __syncthreads();
  __threadfence();  // invalidate local caches before reading meta/perm

  int a0 = xcd << 1;
  int n0 = meta[a0], n1 = meta[a0 + 1];
  int nt0 = (n0 + TR - 1) / TR, nt1 = (n1 + TR - 1) / TR;
  int a, t;
  if (slot < nt0) {
    a = a0; t = slot;
  } else if (slot < nt0 + nt1) {
    a = a0 + 1; t = slot - nt0;
  } else {
    return;
  }
  int rowbase = meta[16 + a] + t * TR;
  int nrows = meta[a] - t * TR;
  nrows = nrows > TR ? TR : nrows;

  int lane = tid & 63;
  int w = tid >> 6;  // 0..15
  int l15 = lane & 15, l4 = lane >> 4;

  // ---- stage X tile -> LDS bf16, swizzle byte ^= (row&7)<<4 ----
  __syncthreads();  // transpose scratch fully consumed before overwrite
  {
#pragma unroll
    for (int it = 0; it < 10; ++it) {
      int c = tid + (it << 10);
      int row = c >> 7, chunk = c & 127;
      int gr = (row < nrows) ? perm[rowbase + row] : -1;
      float4 v = make_float4(0.f, 0.f, 0.f, 0.f);
      if (gr >= 0) v = *(const float4*)(state + (size_t)gr * ND + (chunk << 2));
      uint2 pk;
      pk.x = (unsigned)f2b(v.x) | ((unsigned)f2b(v.y) << 16);
      pk.y = (unsigned)f2b(v.z) | ((unsigned)f2b(v.w) << 16);
      *(uint2*)(Xs + row * 1024 + ((chunk << 3) ^ ((row & 7) << 4))) = pk;
    }
  }

  // ---- wait for this XCD's weights ----
  if (tid == 0) {
    while (__hip_atomic_load(&meta[33 + xcd], __ATOMIC_RELAXED, __HIP_MEMORY_SCOPE_AGENT) < 256) {}
  }
  __syncthreads();  // also covers X-staging completion
  __threadfence();

  // A blob addr: base + ((h>>4)*16 + ks)*1024 + lane*16, h>>4 = w*2 + hf
  const char* Wl = (const char*)W1s + ((size_t)a << 19) + (w << 15) + (lane << 4);
  const char* Wl2 = (const char*)W2s + ((size_t)a << 19) + (w << 15) + (lane << 4);

  bf16x8 A[2][2];
  bf16x8 Bc[5], Bn[5];
#pragma unroll
  for (int s = 0; s < 2; ++s)
#pragma unroll
    for (int hf = 0; hf < 2; ++hf)
      A[s][hf] = *(const bf16x8*)(Wl + (hf << 14) + (s << 10));

  uint2 h1p[10];

  // ---- layer 1: h1 = relu(X @ W1 + b1), [h][b], h1 kept in registers ----
  {
    f32x4 acc[2][5] = {};
#pragma unroll
    for (int bf = 0; bf < 5; ++bf) {
      int b = (bf << 4) + l15;
      Bc[bf] = *(const bf16x8*)(Xs + b * 1024 + ((l4 << 4) ^ ((b & 7) << 4)));
    }
#pragma unroll
    for (int ks = 0; ks < 16; ++ks) {
      if (ks < 15) {
#pragma unroll
        for (int bf = 0; bf < 5; ++bf) {
          int b = (bf << 4) + l15;
          Bn[bf] = *(const bf16x8*)(Xs + b * 1024 + ((((ks + 1) << 6) + (l4 << 4)) ^ ((b & 7) << 4)));
        }
      }
#pragma unroll
      for (int hf = 0; hf < 2; ++hf)
#pragma unroll
        for (int bf = 0; bf < 5; ++bf)
          acc[hf][bf] = __builtin_amdgcn_mfma_f32_16x16x32_bf16(A[ks & 1][hf], Bc[bf], acc[hf][bf], 0, 0, 0);
      if (ks < 14) {
#pragma unroll
        for (int hf = 0; hf < 2; ++hf)
          A[ks & 1][hf] = *(const bf16x8*)(Wl + (hf << 14) + ((ks + 2) << 10));
      }
#pragma unroll
      for (int bf = 0; bf < 5; ++bf) Bc[bf] = Bn[bf];
    }
#pragma unroll
    for (int s = 0; s < 2; ++s)
#pragma unroll
      for (int hf = 0; hf < 2; ++hf)
        A[s][hf] = *(const bf16x8*)(Wl2 + (hf << 14) + (s << 10));
#pragma unroll
    for (int hf = 0; hf < 2; ++hf) {
      int hb = (w << 5) + (hf << 4) + (l4 << 2);
      float4 bias = *(const float4*)(b1 + (a << 9) + hb);
#pragma unroll
      for (int bf = 0; bf < 5; ++bf) {
        float x0 = fmaxf(acc[hf][bf][0] + bias.x, 0.f);
        float x1 = fmaxf(acc[hf][bf][1] + bias.y, 0.f);
        float x2 = fmaxf(acc[hf][bf][2] + bias.z, 0.f);
        float x3 = fmaxf(acc[hf][bf][3] + bias.w, 0.f);
        h1p[hf * 5 + bf].x = (unsigned)f2b(x0) | ((unsigned)f2b(x1) << 16);
        h1p[hf * 5 + bf].y = (unsigned)f2b(x2) | ((unsigned)f2b(x3) << 16);
      }
    }
  }
  __syncthreads();
#pragma unroll
  for (int hf = 0; hf < 2; ++hf) {
    int hb2 = ((w << 5) + (hf << 4) + (l4 << 2)) << 1;
#pragma unroll
    for (int bf = 0; bf < 5; ++bf) {
      int b = (bf << 4) + l15;
      *(uint2*)(Xs + b * 1024 + (hb2 ^ ((b & 7) << 4))) = h1p[hf * 5 + bf];
    }
  }
  __syncthreads();

  // ---- layer 2 + fused layer 3 ----
  {
    f32x4 acc[2][5] = {};
#pragma unroll
    for (int bf = 0; bf < 5; ++bf) {
      int b = (bf << 4) + l15;
      Bc[bf] = *(const bf16x8*)(Xs + b * 1024 + ((l4 << 4) ^ ((b & 7) << 4)));
    }
#pragma unroll
    for (int ks = 0; ks < 16; ++ks) {
      if (ks < 15) {
#pragma unroll
        for (int bf = 0; bf < 5; ++bf) {
          int b = (bf << 4) + l15;
          Bn[bf] = *(const bf16x8*)(Xs + b * 1024 + ((((ks + 1) << 6) + (l4 << 4)) ^ ((b & 7) << 4)));
        }
      }
#pragma unroll
      for (int hf = 0; hf < 2; ++hf)
#pragma unroll
        for (int bf = 0; bf < 5; ++bf)
          acc[hf][bf] = __builtin_amdgcn_mfma_f32_16x16x32_bf16(A[ks & 1][hf], Bc[bf], acc[hf][bf], 0, 0, 0);
      if (ks < 14) {
#pragma unroll
        for (int hf = 0; hf < 2; ++hf)
          A[ks & 1][hf] = *(const bf16x8*)(Wl2 + (hf << 14) + ((ks + 2) << 10));
      }
#pragma unroll
      for (int bf = 0; bf < 5; ++bf) Bc[bf] = Bn[bf];
    }
    float part[5] = {0.f, 0.f, 0.f, 0.f, 0.f};
#pragma unroll
    for (int hf = 0; hf < 2; ++hf) {
      int hb = (w << 5) + (hf << 4) + (l4 << 2);
      float4 bias = *(const float4*)(b2 + (a << 9) + hb);
      float4 w3v = *(const float4*)(W3 + (a << 9) + hb);
#pragma unroll
      for (int bf = 0; bf < 5; ++bf) {
        part[bf] += fmaxf(acc[hf][bf][0] + bias.x, 0.f) * w3v.x +
                    fmaxf(acc[hf][bf][1] + bias.y, 0.f) * w3v.y +
                    fmaxf(acc[hf][bf][2] + bias.z, 0.f) * w3v.z +
                    fmaxf(acc[hf][bf][3] + bias.w, 0.f) * w3v.w;
      }
    }
#pragma unroll
    for (int bf = 0; bf < 5; ++bf) {
      float p = part[bf];
      p += __shfl_xor(p, 16);
      p += __shfl_xor(p, 32);
      if (l4 == 0) outbuf[w * TR + (bf << 4) + l15] = p;
    }
  }
  __syncthreads();
  if (tid < nrows) {
    float s = b3[a];
#pragma unroll
    for (int ww = 0; ww < 16; ++ww) s += outbuf[ww * TR + tid];
    out[perm[rowbase + tid]] = s;
  }
}

extern "C" void kernel_launch(void* const* d_in, const int* in_sizes, int n_in,
                              void* d_out, int out_size, void* d_ws, size_t ws_size,
                              hipStream_t stream) {
  const float* state = (const float*)d_in[0];
  const float* W1 = (const float*)d_in[1];
  const float* b1 = (const float*)d_in[2];
  const float* W2 = (const float*)d_in[3];
  const float* b2 = (const float*)d_in[4];
  const float* W3 = (const float*)d_in[5];
  const float* b3 = (const float*)d_in[6];
  const int* actions = (const int*)d_in[7];
  float* out = (float*)d_out;
  char* ws = (char*)d_ws;
  bf16* W1s = (bf16*)(ws + W1S_OFF);
  bf16* W2s = (bf16*)(ws + W2S_OFF);
  int* perm = (int*)(ws + PERM_OFF);
  int* meta = (int*)(ws + META_OFF);

  hipMemsetAsync(meta, 0, 48 * sizeof(int), stream);  // zero cnt/off/flags each replay
  hipFuncSetAttribute((const void*)k_fused, hipFuncAttributeMaxDynamicSharedMemorySize, 87040);
  k_fused<<<256, 1024, 87040, stream>>>(state, W1, b1, W2, b2, W3, b3, actions,
                                        W1s, W2s, perm, meta, out);
}

// Round 15
// 49.105 us; speedup vs baseline: 4.0070x; 4.0070x over previous
//
#include <hip/hip_runtime.h>
#include <hip/hip_bf16.h>
#include <stdint.h>

typedef __hip_bfloat16 bf16;
typedef float f32x4 __attribute__((ext_vector_type(4)));
typedef short bf16x8 __attribute__((ext_vector_type(8)));

#define NB 16384
#define NA 16
#define ND 512
#define NH 512
#define TR 80  // rows/tile: 13 tiles/action, 26/XCD-pair <= 32 CUs -> all resident, no tail

// workspace layout (bytes)
#define W1S_OFF 0u
#define W2S_OFF 8388608u
#define PERM_OFF 16777216u
#define META_OFF 16842752u
// meta ints: [0..15]=cnt, [16..31]=off

__device__ __forceinline__ unsigned short f2b(float x) {
  unsigned int b = __float_as_uint(x);
  return (unsigned short)((b + 0x7FFFu + ((b >> 16) & 1u)) >> 16);  // RNE
}

// ---------------- prep: pipelined W transpose (blocks 0..511) + meta (block 512) ----------
// Each transpose block: 4 tiles, double-buffered LDS; tile r+1's HBM loads issue while
// tile r converts/stores (hides ~900cy load latency). XCD-pinned: bid&7==x handles
// actions 2x,2x+1. Weight layout per action: blob[(h>>4)*16 + (k>>5)] of 1KB; byte =
// ((k>>3)&3)*256 + (h&15)*16 + (k&7)*2.  Wave emits whole blobs (lane l -> blob+l*16).
__global__ __launch_bounds__(256) void k_prep(const float* __restrict__ W1,
                                              const float* __restrict__ W2,
                                              bf16* __restrict__ W1s,
                                              bf16* __restrict__ W2s,
                                              const int* __restrict__ act,
                                              int* __restrict__ meta,
                                              int* __restrict__ perm) {
  __shared__ union {
    float tile[2][64][65];
    struct { int hist[16][256]; int off16[16]; } m;
  } lds;
  if (blockIdx.x == 512) {
    // ---- meta: hist + wave-scan + scatter (parallel, ~8us, concurrent w/ transposes) ----
    int t = threadIdx.x;
    int lane = t & 63, wv = t >> 6;
#pragma unroll
    for (int i = 0; i < 16; ++i) lds.m.hist[i][t] = 0;
    __syncthreads();
    for (int j = 0; j < 64; ++j) {
      int a = act[t + (j << 8)] & 15;
      lds.m.hist[a][t]++;
    }
    __syncthreads();
    for (int q = 0; q < 4; ++q) {
      int a = (wv << 2) + q;
      int base = lane << 2;
      int v0 = lds.m.hist[a][base + 0];
      int v1 = lds.m.hist[a][base + 1];
      int v2 = lds.m.hist[a][base + 2];
      int v3 = lds.m.hist[a][base + 3];
      int s = v0 + v1 + v2 + v3;
      int incl = s;
#pragma unroll
      for (int d = 1; d < 64; d <<= 1) {
        int y = __shfl_up(incl, d);
        if (lane >= d) incl += y;
      }
      int excl = incl - s;
      lds.m.hist[a][base + 0] = excl;
      lds.m.hist[a][base + 1] = excl + v0;
      lds.m.hist[a][base + 2] = excl + v0 + v1;
      lds.m.hist[a][base + 3] = excl + v0 + v1 + v2;
      if (lane == 63) lds.m.off16[a] = incl;
    }
    __syncthreads();
    if (t == 0) {
      int o = 0;
      for (int aa = 0; aa < 16; ++aa) {
        int c = lds.m.off16[aa];
        meta[aa] = c;
        meta[16 + aa] = o;
        lds.m.off16[aa] = o;
        o += c;
      }
    }
    __syncthreads();
    for (int j = 0; j < 64; ++j) {
      int idx = t + (j << 8);
      int a = act[idx] & 15;
      int pos = lds.m.off16[a] + lds.m.hist[a][t]++;
      perm[pos] = idx;
    }
    return;
  }
  int bid = blockIdx.x;          // 0..511
  int xcd = bid & 7, q = bid >> 3;  // q: 0..63
  int t = threadIdx.x;
  int r0 = t >> 2, c0 = (t & 3) << 4;
  int wv = t >> 6, l = t & 63;
  int l15b = l & 15, l4b = l >> 4;

  float4 v[4];
  char* dstb_r[4];
  int td_r[4], th_r[4];
#pragma unroll
  for (int r = 0; r < 4; ++r) {
    int jj = q + (r << 6);       // 0..255 within this XCD's 4 matrices
    int mi = jj >> 6;            // 0..3: W1[2x], W1[2x+1], W2[2x], W2[2x+1]
    int mat = (mi < 2) ? ((xcd << 1) + mi) : (NA + (xcd << 1) + (mi - 2));
    dstb_r[r] = (mat < NA) ? ((char*)W1s + ((size_t)mat << 19))
                           : ((char*)W2s + ((size_t)(mat - NA) << 19));
    int tl = jj & 63;
    td_r[r] = tl >> 3;
    th_r[r] = tl & 7;
  }
  // preload tile 0
  {
    int mi0 = q >> 6;  // q<64 -> always 0; matrix W1[2x]
    const float* src = W1 + (size_t)((xcd << 1) + mi0) * (ND * NH);
    const float* sp = src + (size_t)(td_r[0] * 64 + r0) * NH + th_r[0] * 64 + c0;
    v[0] = ((const float4*)sp)[0];
    v[1] = ((const float4*)sp)[1];
    v[2] = ((const float4*)sp)[2];
    v[3] = ((const float4*)sp)[3];
  }
#pragma unroll
  for (int r = 0; r < 4; ++r) {
    int buf = r & 1;
    float* trp = &lds.tile[buf][r0][c0];
    trp[0] = v[0].x; trp[1] = v[0].y; trp[2] = v[0].z; trp[3] = v[0].w;
    trp[4] = v[1].x; trp[5] = v[1].y; trp[6] = v[1].z; trp[7] = v[1].w;
    trp[8] = v[2].x; trp[9] = v[2].y; trp[10] = v[2].z; trp[11] = v[2].w;
    trp[12] = v[3].x; trp[13] = v[3].y; trp[14] = v[3].z; trp[15] = v[3].w;
    __syncthreads();
    if (r < 3) {  // issue next tile's loads; latency hides under convert/store below
      int jj = q + ((r + 1) << 6);
      int mi = jj >> 6;
      int mat = (mi < 2) ? ((xcd << 1) + mi) : (NA + (xcd << 1) + (mi - 2));
      const float* src = (mat < NA) ? (W1 + (size_t)mat * (ND * NH))
                                    : (W2 + (size_t)(mat - NA) * (ND * NH));
      const float* sp = src + (size_t)(td_r[r + 1] * 64 + r0) * NH + th_r[r + 1] * 64 + c0;
      v[0] = ((const float4*)sp)[0];
      v[1] = ((const float4*)sp)[1];
      v[2] = ((const float4*)sp)[2];
      v[3] = ((const float4*)sp)[3];
    }
#pragma unroll
    for (int kc = 0; kc < 2; ++kc) {
      union { unsigned short us[8]; uint4 qd; } u;
#pragma unroll
      for (int i = 0; i < 8; ++i)
        u.us[i] = f2b(lds.tile[buf][kc * 32 + l4b * 8 + i][wv * 16 + l15b]);
      int hb = th_r[r] * 4 + wv;
      int kb = td_r[r] * 2 + kc;
      *(uint4*)(dstb_r[r] + ((size_t)(hb * 16 + kb) << 10) + (l << 4)) = u.qd;
    }
    // next iter writes buf^1 (safe); buf rewritten only after the next barrier
  }
}

// ---------------- fused grouped MLP (byte-identical to round 13) ----------------
// XCD x (bid&7) owns actions 2x,2x+1 (2MB L2 set). Grid 256 = 32 slots/XCD, 26 tiles/pair.
// Block: 80-row tile, 1024 threads = 16 waves (4/SIMD); wave w owns h [w*32, w*32+32).
// Small per-wave regs (A[2][2] depth-2 pipeline, acc[2][5]) to fit the 128-VGPR cap.
// LDS: Xs 80KB @0 (X, then h1 via register round-trip), outbuf 5KB @81920.
__global__ __launch_bounds__(1024) void k_main(
    const float* __restrict__ state, const float* __restrict__ b1,
    const float* __restrict__ b2, const float* __restrict__ W3,
    const float* __restrict__ b3, const bf16* __restrict__ W1s,
    const bf16* __restrict__ W2s, const int* __restrict__ perm,
    const int* __restrict__ meta, float* __restrict__ out) {
  extern __shared__ char smem[];
  char* Xs = smem;
  float* outbuf = (float*)(smem + 81920);

  int bid = blockIdx.x;
  int xcd = bid & 7, slot = bid >> 3;
  int a0 = xcd << 1;
  int n0 = meta[a0], n1 = meta[a0 + 1];
  int nt0 = (n0 + TR - 1) / TR, nt1 = (n1 + TR - 1) / TR;
  int a, t;
  if (slot < nt0) {
    a = a0; t = slot;
  } else if (slot < nt0 + nt1) {
    a = a0 + 1; t = slot - nt0;
  } else {
    return;
  }
  int rowbase = meta[16 + a] + t * TR;
  int nrows = meta[a] - t * TR;
  nrows = nrows > TR ? TR : nrows;

  int tid = threadIdx.x;
  int lane = tid & 63;
  int w = tid >> 6;  // 0..15
  int l15 = lane & 15, l4 = lane >> 4;

  // A blob addr: base + ((h>>4)*16 + ks)*1024 + lane*16, h>>4 = w*2 + hf
  const char* Wl = (const char*)W1s + ((size_t)a << 19) + (w << 15) + (lane << 4);
  const char* Wl2 = (const char*)W2s + ((size_t)a << 19) + (w << 15) + (lane << 4);

  bf16x8 A[2][2];  // [ks&1][hf] depth-2 pipeline
  bf16x8 Bc[5], Bn[5];
#pragma unroll
  for (int s = 0; s < 2; ++s)
#pragma unroll
    for (int hf = 0; hf < 2; ++hf)
      A[s][hf] = *(const bf16x8*)(Wl + (hf << 14) + (s << 10));

  // ---- stage X tile -> LDS bf16, swizzle byte ^= (row&7)<<4 ----
  {
#pragma unroll
    for (int it = 0; it < 10; ++it) {
      int c = tid + (it << 10);      // 0..10239
      int row = c >> 7, chunk = c & 127;
      int gr = (row < nrows) ? perm[rowbase + row] : -1;
      float4 v = make_float4(0.f, 0.f, 0.f, 0.f);
      if (gr >= 0) v = *(const float4*)(state + (size_t)gr * ND + (chunk << 2));
      uint2 pk;
      pk.x = (unsigned)f2b(v.x) | ((unsigned)f2b(v.y) << 16);
      pk.y = (unsigned)f2b(v.z) | ((unsigned)f2b(v.w) << 16);
      *(uint2*)(Xs + row * 1024 + ((chunk << 3) ^ ((row & 7) << 4))) = pk;
    }
  }
  __syncthreads();

  uint2 h1p[10];

  // ---- layer 1: h1 = relu(X @ W1 + b1), [h][b], h1 kept in registers ----
  {
    f32x4 acc[2][5] = {};
#pragma unroll
    for (int bf = 0; bf < 5; ++bf) {
      int b = (bf << 4) + l15;
      Bc[bf] = *(const bf16x8*)(Xs + b * 1024 + ((l4 << 4) ^ ((b & 7) << 4)));
    }
#pragma unroll
    for (int ks = 0; ks < 16; ++ks) {
      if (ks < 15) {
#pragma unroll
        for (int bf = 0; bf < 5; ++bf) {
          int b = (bf << 4) + l15;
          Bn[bf] = *(const bf16x8*)(Xs + b * 1024 + ((((ks + 1) << 6) + (l4 << 4)) ^ ((b & 7) << 4)));
        }
      }
#pragma unroll
      for (int hf = 0; hf < 2; ++hf)
#pragma unroll
        for (int bf = 0; bf < 5; ++bf)
          acc[hf][bf] = __builtin_amdgcn_mfma_f32_16x16x32_bf16(A[ks & 1][hf], Bc[bf], acc[hf][bf], 0, 0, 0);
      if (ks < 14) {
#pragma unroll
        for (int hf = 0; hf < 2; ++hf)
          A[ks & 1][hf] = *(const bf16x8*)(Wl + (hf << 14) + ((ks + 2) << 10));
      }
#pragma unroll
      for (int bf = 0; bf < 5; ++bf) Bc[bf] = Bn[bf];
    }
    // layer-2 A preloads; latency hides under epilogue + barriers
#pragma unroll
    for (int s = 0; s < 2; ++s)
#pragma unroll
      for (int hf = 0; hf < 2; ++hf)
        A[s][hf] = *(const bf16x8*)(Wl2 + (hf << 14) + (s << 10));
    // epilogue: bias + relu + pack bf16 into registers
#pragma unroll
    for (int hf = 0; hf < 2; ++hf) {
      int hb = (w << 5) + (hf << 4) + (l4 << 2);
      float4 bias = *(const float4*)(b1 + (a << 9) + hb);
#pragma unroll
      for (int bf = 0; bf < 5; ++bf) {
        float x0 = fmaxf(acc[hf][bf][0] + bias.x, 0.f);
        float x1 = fmaxf(acc[hf][bf][1] + bias.y, 0.f);
        float x2 = fmaxf(acc[hf][bf][2] + bias.z, 0.f);
        float x3 = fmaxf(acc[hf][bf][3] + bias.w, 0.f);
        h1p[hf * 5 + bf].x = (unsigned)f2b(x0) | ((unsigned)f2b(x1) << 16);
        h1p[hf * 5 + bf].y = (unsigned)f2b(x2) | ((unsigned)f2b(x3) << 16);
      }
    }
  }
  __syncthreads();  // all waves done reading X
#pragma unroll
  for (int hf = 0; hf < 2; ++hf) {
    int hb2 = ((w << 5) + (hf << 4) + (l4 << 2)) << 1;  // byte offset within row
#pragma unroll
    for (int bf = 0; bf < 5; ++bf) {
      int b = (bf << 4) + l15;
      *(uint2*)(Xs + b * 1024 + (hb2 ^ ((b & 7) << 4))) = h1p[hf * 5 + bf];
    }
  }
  __syncthreads();

  // ---- layer 2 + fused layer 3: out = relu(h1 @ W2 + b2) . W3 + b3 ----
  {
    f32x4 acc[2][5] = {};
#pragma unroll
    for (int bf = 0; bf < 5; ++bf) {
      int b = (bf << 4) + l15;
      Bc[bf] = *(const bf16x8*)(Xs + b * 1024 + ((l4 << 4) ^ ((b & 7) << 4)));
    }
#pragma unroll
    for (int ks = 0; ks < 16; ++ks) {
      if (ks < 15) {
#pragma unroll
        for (int bf = 0; bf < 5; ++bf) {
          int b = (bf << 4) + l15;
          Bn[bf] = *(const bf16x8*)(Xs + b * 1024 + ((((ks + 1) << 6) + (l4 << 4)) ^ ((b & 7) << 4)));
        }
      }
#pragma unroll
      for (int hf = 0; hf < 2; ++hf)
#pragma unroll
        for (int bf = 0; bf < 5; ++bf)
          acc[hf][bf] = __builtin_amdgcn_mfma_f32_16x16x32_bf16(A[ks & 1][hf], Bc[bf], acc[hf][bf], 0, 0, 0);
      if (ks < 14) {
#pragma unroll
        for (int hf = 0; hf < 2; ++hf)
          A[ks & 1][hf] = *(const bf16x8*)(Wl2 + (hf << 14) + ((ks + 2) << 10));
      }
#pragma unroll
      for (int bf = 0; bf < 5; ++bf) Bc[bf] = Bn[bf];
    }
    float part[5] = {0.f, 0.f, 0.f, 0.f, 0.f};
#pragma unroll
    for (int hf = 0; hf < 2; ++hf) {
      int hb = (w << 5) + (hf << 4) + (l4 << 2);
      float4 bias = *(const float4*)(b2 + (a << 9) + hb);
      float4 w3v = *(const float4*)(W3 + (a << 9) + hb);
#pragma unroll
      for (int bf = 0; bf < 5; ++bf) {
        part[bf] += fmaxf(acc[hf][bf][0] + bias.x, 0.f) * w3v.x +
                    fmaxf(acc[hf][bf][1] + bias.y, 0.f) * w3v.y +
                    fmaxf(acc[hf][bf][2] + bias.z, 0.f) * w3v.z +
                    fmaxf(acc[hf][bf][3] + bias.w, 0.f) * w3v.w;
      }
    }
#pragma unroll
    for (int bf = 0; bf < 5; ++bf) {
      float p = part[bf];
      p += __shfl_xor(p, 16);
      p += __shfl_xor(p, 32);
      if (l4 == 0) outbuf[w * TR + (bf << 4) + l15] = p;
    }
  }
  __syncthreads();
  if (tid < nrows) {
    float s = b3[a];
#pragma unroll
    for (int ww = 0; ww < 16; ++ww) s += outbuf[ww * TR + tid];
    out[perm[rowbase + tid]] = s;
  }
}

extern "C" void kernel_launch(void* const* d_in, const int* in_sizes, int n_in,
                              void* d_out, int out_size, void* d_ws, size_t ws_size,
                              hipStream_t stream) {
  const float* state = (const float*)d_in[0];
  const float* W1 = (const float*)d_in[1];
  const float* b1 = (const float*)d_in[2];
  const float* W2 = (const float*)d_in[3];
  const float* b2 = (const float*)d_in[4];
  const float* W3 = (const float*)d_in[5];
  const float* b3 = (const float*)d_in[6];
  const int* actions = (const int*)d_in[7];
  float* out = (float*)d_out;
  char* ws = (char*)d_ws;
  bf16* W1s = (bf16*)(ws + W1S_OFF);
  bf16* W2s = (bf16*)(ws + W2S_OFF);
  int* perm = (int*)(ws + PERM_OFF);
  int* meta = (int*)(ws + META_OFF);

  k_prep<<<513, 256, 0, stream>>>(W1, W2, W1s, W2s, actions, meta, perm);
  hipFuncSetAttribute((const void*)k_main, hipFuncAttributeMaxDynamicSharedMemorySize, 87040);
  k_main<<<256, 1024, 87040, stream>>>(state, b1, b2, W3, b3, W1s, W2s, perm, meta, out);
}

// Round 16
// 48.684 us; speedup vs baseline: 4.0417x; 1.0087x over previous
//
#include <hip/hip_runtime.h>
#include <hip/hip_bf16.h>
#include <stdint.h>

typedef __hip_bfloat16 bf16;
typedef float f32x4 __attribute__((ext_vector_type(4)));
typedef short bf16x8 __attribute__((ext_vector_type(8)));

#define NB 16384
#define NA 16
#define ND 512
#define NH 512
#define TR 80  // rows/tile: 13-14 tiles/action, <=28/XCD-pair <= 32 CUs -> no tail

// workspace layout (bytes)
#define W1S_OFF 0u
#define W2S_OFF 8388608u
#define PERM_OFF 16777216u
#define META_OFF 16842752u
// meta ints: [0..15]=cnt, [16..31]=off

__device__ __forceinline__ unsigned short f2b(float x) {
  unsigned int b = __float_as_uint(x);
  return (unsigned short)((b + 0x7FFFu + ((b >> 16) & 1u)) >> 16);  // RNE
}

// ---------------- prep: pipelined W transpose (blocks 0..511) + meta (block 512) ----------
// (unchanged from round 15)
__global__ __launch_bounds__(256) void k_prep(const float* __restrict__ W1,
                                              const float* __restrict__ W2,
                                              bf16* __restrict__ W1s,
                                              bf16* __restrict__ W2s,
                                              const int* __restrict__ act,
                                              int* __restrict__ meta,
                                              int* __restrict__ perm) {
  __shared__ union {
    float tile[2][64][65];
    struct { int hist[16][256]; int off16[16]; } m;
  } lds;
  if (blockIdx.x == 512) {
    int t = threadIdx.x;
    int lane = t & 63, wv = t >> 6;
#pragma unroll
    for (int i = 0; i < 16; ++i) lds.m.hist[i][t] = 0;
    __syncthreads();
    for (int j = 0; j < 64; ++j) {
      int a = act[t + (j << 8)] & 15;
      lds.m.hist[a][t]++;
    }
    __syncthreads();
    for (int q = 0; q < 4; ++q) {
      int a = (wv << 2) + q;
      int base = lane << 2;
      int v0 = lds.m.hist[a][base + 0];
      int v1 = lds.m.hist[a][base + 1];
      int v2 = lds.m.hist[a][base + 2];
      int v3 = lds.m.hist[a][base + 3];
      int s = v0 + v1 + v2 + v3;
      int incl = s;
#pragma unroll
      for (int d = 1; d < 64; d <<= 1) {
        int y = __shfl_up(incl, d);
        if (lane >= d) incl += y;
      }
      int excl = incl - s;
      lds.m.hist[a][base + 0] = excl;
      lds.m.hist[a][base + 1] = excl + v0;
      lds.m.hist[a][base + 2] = excl + v0 + v1;
      lds.m.hist[a][base + 3] = excl + v0 + v1 + v2;
      if (lane == 63) lds.m.off16[a] = incl;
    }
    __syncthreads();
    if (t == 0) {
      int o = 0;
      for (int aa = 0; aa < 16; ++aa) {
        int c = lds.m.off16[aa];
        meta[aa] = c;
        meta[16 + aa] = o;
        lds.m.off16[aa] = o;
        o += c;
      }
    }
    __syncthreads();
    for (int j = 0; j < 64; ++j) {
      int idx = t + (j << 8);
      int a = act[idx] & 15;
      int pos = lds.m.off16[a] + lds.m.hist[a][t]++;
      perm[pos] = idx;
    }
    return;
  }
  int bid = blockIdx.x;          // 0..511
  int xcd = bid & 7, q = bid >> 3;  // q: 0..63
  int t = threadIdx.x;
  int r0 = t >> 2, c0 = (t & 3) << 4;
  int wv = t >> 6, l = t & 63;
  int l15b = l & 15, l4b = l >> 4;

  float4 v[4];
  char* dstb_r[4];
  int td_r[4], th_r[4];
#pragma unroll
  for (int r = 0; r < 4; ++r) {
    int jj = q + (r << 6);
    int mi = jj >> 6;
    int mat = (mi < 2) ? ((xcd << 1) + mi) : (NA + (xcd << 1) + (mi - 2));
    dstb_r[r] = (mat < NA) ? ((char*)W1s + ((size_t)mat << 19))
                           : ((char*)W2s + ((size_t)(mat - NA) << 19));
    int tl = jj & 63;
    td_r[r] = tl >> 3;
    th_r[r] = tl & 7;
  }
  {
    int mi0 = q >> 6;
    const float* src = W1 + (size_t)((xcd << 1) + mi0) * (ND * NH);
    const float* sp = src + (size_t)(td_r[0] * 64 + r0) * NH + th_r[0] * 64 + c0;
    v[0] = ((const float4*)sp)[0];
    v[1] = ((const float4*)sp)[1];
    v[2] = ((const float4*)sp)[2];
    v[3] = ((const float4*)sp)[3];
  }
#pragma unroll
  for (int r = 0; r < 4; ++r) {
    int buf = r & 1;
    float* trp = &lds.tile[buf][r0][c0];
    trp[0] = v[0].x; trp[1] = v[0].y; trp[2] = v[0].z; trp[3] = v[0].w;
    trp[4] = v[1].x; trp[5] = v[1].y; trp[6] = v[1].z; trp[7] = v[1].w;
    trp[8] = v[2].x; trp[9] = v[2].y; trp[10] = v[2].z; trp[11] = v[2].w;
    trp[12] = v[3].x; trp[13] = v[3].y; trp[14] = v[3].z; trp[15] = v[3].w;
    __syncthreads();
    if (r < 3) {
      int jj = q + ((r + 1) << 6);
      int mi = jj >> 6;
      int mat = (mi < 2) ? ((xcd << 1) + mi) : (NA + (xcd << 1) + (mi - 2));
      const float* src = (mat < NA) ? (W1 + (size_t)mat * (ND * NH))
                                    : (W2 + (size_t)(mat - NA) * (ND * NH));
      const float* sp = src + (size_t)(td_r[r + 1] * 64 + r0) * NH + th_r[r + 1] * 64 + c0;
      v[0] = ((const float4*)sp)[0];
      v[1] = ((const float4*)sp)[1];
      v[2] = ((const float4*)sp)[2];
      v[3] = ((const float4*)sp)[3];
    }
#pragma unroll
    for (int kc = 0; kc < 2; ++kc) {
      union { unsigned short us[8]; uint4 qd; } u;
#pragma unroll
      for (int i = 0; i < 8; ++i)
        u.us[i] = f2b(lds.tile[buf][kc * 32 + l4b * 8 + i][wv * 16 + l15b]);
      int hb = th_r[r] * 4 + wv;
      int kb = td_r[r] * 2 + kc;
      *(uint4*)(dstb_r[r] + ((size_t)(hb * 16 + kb) << 10) + (l << 4)) = u.qd;
    }
  }
}

// ---------------- fused grouped MLP: slab-pipelined X staging ----------------
// XCD x (bid&7) owns actions 2x,2x+1. Grid 256 = 32 slots/XCD, ~26 tiles/pair.
// Block: 80-row tile, 1024 threads = 16 waves (4/SIMD); wave w owns h [w*32,+32).
// X staged in 4 k-slabs of 128: slab s+1's gathers issue at slab-s top, ds-writes
// land after 4 ks of MFMA (compiler inserts the vmcnt for the data dep), 1 barrier/slab.
// LDS: Xs 80KB @0 (X, then h1), outbuf 5KB @81920.
__global__ __launch_bounds__(1024) void k_main(
    const float* __restrict__ state, const float* __restrict__ b1,
    const float* __restrict__ b2, const float* __restrict__ W3,
    const float* __restrict__ b3, const bf16* __restrict__ W1s,
    const bf16* __restrict__ W2s, const int* __restrict__ perm,
    const int* __restrict__ meta, float* __restrict__ out) {
  extern __shared__ char smem[];
  char* Xs = smem;
  float* outbuf = (float*)(smem + 81920);

  int bid = blockIdx.x;
  int xcd = bid & 7, slot = bid >> 3;
  int a0 = xcd << 1;
  int n0 = meta[a0], n1 = meta[a0 + 1];
  int nt0 = (n0 + TR - 1) / TR, nt1 = (n1 + TR - 1) / TR;
  int a, t;
  if (slot < nt0) {
    a = a0; t = slot;
  } else if (slot < nt0 + nt1) {
    a = a0 + 1; t = slot - nt0;
  } else {
    return;
  }
  int rowbase = meta[16 + a] + t * TR;
  int nrows = meta[a] - t * TR;
  nrows = nrows > TR ? TR : nrows;

  int tid = threadIdx.x;
  int lane = tid & 63;
  int w = tid >> 6;  // 0..15
  int l15 = lane & 15, l4 = lane >> 4;

  // staging geometry: slab = 128 k (512B f32/row); 80 rows x 32 chunks = 2560 chunks;
  // thread handles chunks c = tid, tid+1024, tid+2048 (c<2560)
  int srow[3], skc[3];
  const float* sptr[3];
  bool sval[3];
#pragma unroll
  for (int i = 0; i < 3; ++i) {
    int c = tid + (i << 10);
    sval[i] = c < 2560;
    srow[i] = c >> 5;
    skc[i] = c & 31;
    int gr = (sval[i] && srow[i] < nrows) ? perm[rowbase + srow[i]] : -1;
    sptr[i] = (gr >= 0) ? (state + (size_t)gr * ND) : nullptr;
  }

  // A blob addr: base + ((h>>4)*16 + ks)*1024 + lane*16, h>>4 = w*2 + hf
  const char* Wl = (const char*)W1s + ((size_t)a << 19) + (w << 15) + (lane << 4);
  const char* Wl2 = (const char*)W2s + ((size_t)a << 19) + (w << 15) + (lane << 4);

  bf16x8 A[2][2];  // [ks&1][hf] depth-2 pipeline
  bf16x8 Bc[5];
#pragma unroll
  for (int s = 0; s < 2; ++s)
#pragma unroll
    for (int hf = 0; hf < 2; ++hf)
      A[s][hf] = *(const bf16x8*)(Wl + (hf << 14) + (s << 10));

  // ---- stage slab 0 ----
  {
#pragma unroll
    for (int i = 0; i < 3; ++i) {
      if (!sval[i]) continue;
      float4 v = sptr[i] ? *(const float4*)(sptr[i] + (skc[i] << 2)) : make_float4(0.f, 0.f, 0.f, 0.f);
      uint2 pk;
      pk.x = (unsigned)f2b(v.x) | ((unsigned)f2b(v.y) << 16);
      pk.y = (unsigned)f2b(v.z) | ((unsigned)f2b(v.w) << 16);
      *(uint2*)(Xs + srow[i] * 1024 + ((skc[i] << 3) ^ ((srow[i] & 7) << 4))) = pk;
    }
  }
  __syncthreads();

  uint2 h1p[10];

  // ---- layer 1: slab-pipelined ----
  {
    f32x4 acc[2][5] = {};
#pragma unroll
    for (int s = 0; s < 4; ++s) {
      float4 g0, g1, g2;
      if (s < 3) {  // issue slab s+1 gathers; land during the 4-ks compute below
        g0 = (sval[0] && sptr[0]) ? *(const float4*)(sptr[0] + ((s + 1) << 7) + (skc[0] << 2)) : make_float4(0.f, 0.f, 0.f, 0.f);
        g1 = (sval[1] && sptr[1]) ? *(const float4*)(sptr[1] + ((s + 1) << 7) + (skc[1] << 2)) : make_float4(0.f, 0.f, 0.f, 0.f);
        g2 = (sval[2] && sptr[2]) ? *(const float4*)(sptr[2] + ((s + 1) << 7) + (skc[2] << 2)) : make_float4(0.f, 0.f, 0.f, 0.f);
      }
#pragma unroll
      for (int kk = 0; kk < 4; ++kk) {
        int ks = (s << 2) + kk;
#pragma unroll
        for (int bf = 0; bf < 5; ++bf) {
          int b = (bf << 4) + l15;
          Bc[bf] = *(const bf16x8*)(Xs + b * 1024 + (((ks << 6) + (l4 << 4)) ^ ((b & 7) << 4)));
        }
        __builtin_amdgcn_s_setprio(1);
#pragma unroll
        for (int hf = 0; hf < 2; ++hf)
#pragma unroll
          for (int bf = 0; bf < 5; ++bf)
            acc[hf][bf] = __builtin_amdgcn_mfma_f32_16x16x32_bf16(A[ks & 1][hf], Bc[bf], acc[hf][bf], 0, 0, 0);
        __builtin_amdgcn_s_setprio(0);
        if (ks < 14) {
#pragma unroll
          for (int hf = 0; hf < 2; ++hf)
            A[ks & 1][hf] = *(const bf16x8*)(Wl + (hf << 14) + ((ks + 2) << 10));
        }
      }
      if (s < 3) {  // write slab s+1 (compiler waits vmcnt for g*)
        int so = (s + 1) << 8;  // byte offset of slab within row
        uint2 pk;
        if (sval[0]) {
          pk.x = (unsigned)f2b(g0.x) | ((unsigned)f2b(g0.y) << 16);
          pk.y = (unsigned)f2b(g0.z) | ((unsigned)f2b(g0.w) << 16);
          *(uint2*)(Xs + srow[0] * 1024 + ((so + (skc[0] << 3)) ^ ((srow[0] & 7) << 4))) = pk;
        }
        if (sval[1]) {
          pk.x = (unsigned)f2b(g1.x) | ((unsigned)f2b(g1.y) << 16);
          pk.y = (unsigned)f2b(g1.z) | ((unsigned)f2b(g1.w) << 16);
          *(uint2*)(Xs + srow[1] * 1024 + ((so + (skc[1] << 3)) ^ ((srow[1] & 7) << 4))) = pk;
        }
        if (sval[2]) {
          pk.x = (unsigned)f2b(g2.x) | ((unsigned)f2b(g2.y) << 16);
          pk.y = (unsigned)f2b(g2.z) | ((unsigned)f2b(g2.w) << 16);
          *(uint2*)(Xs + srow[2] * 1024 + ((so + (skc[2] << 3)) ^ ((srow[2] & 7) << 4))) = pk;
        }
      }
      __syncthreads();
    }
    // layer-2 A preloads; latency hides under epilogue + barriers
#pragma unroll
    for (int s = 0; s < 2; ++s)
#pragma unroll
      for (int hf = 0; hf < 2; ++hf)
        A[s][hf] = *(const bf16x8*)(Wl2 + (hf << 14) + (s << 10));
    // epilogue: bias + relu + pack bf16 into registers
#pragma unroll
    for (int hf = 0; hf < 2; ++hf) {
      int hb = (w << 5) + (hf << 4) + (l4 << 2);
      float4 bias = *(const float4*)(b1 + (a << 9) + hb);
#pragma unroll
      for (int bf = 0; bf < 5; ++bf) {
        float x0 = fmaxf(acc[hf][bf][0] + bias.x, 0.f);
        float x1 = fmaxf(acc[hf][bf][1] + bias.y, 0.f);
        float x2 = fmaxf(acc[hf][bf][2] + bias.z, 0.f);
        float x3 = fmaxf(acc[hf][bf][3] + bias.w, 0.f);
        h1p[hf * 5 + bf].x = (unsigned)f2b(x0) | ((unsigned)f2b(x1) << 16);
        h1p[hf * 5 + bf].y = (unsigned)f2b(x2) | ((unsigned)f2b(x3) << 16);
      }
    }
  }
  __syncthreads();  // all waves done reading X
#pragma unroll
  for (int hf = 0; hf < 2; ++hf) {
    int hb2 = ((w << 5) + (hf << 4) + (l4 << 2)) << 1;
#pragma unroll
    for (int bf = 0; bf < 5; ++bf) {
      int b = (bf << 4) + l15;
      *(uint2*)(Xs + b * 1024 + (hb2 ^ ((b & 7) << 4))) = h1p[hf * 5 + bf];
    }
  }
  __syncthreads();

  // ---- layer 2 + fused layer 3 ----
  {
    f32x4 acc[2][5] = {};
#pragma unroll
    for (int ks = 0; ks < 16; ++ks) {
#pragma unroll
      for (int bf = 0; bf < 5; ++bf) {
        int b = (bf << 4) + l15;
        Bc[bf] = *(const bf16x8*)(Xs + b * 1024 + (((ks << 6) + (l4 << 4)) ^ ((b & 7) << 4)));
      }
      __builtin_amdgcn_s_setprio(1);
#pragma unroll
      for (int hf = 0; hf < 2; ++hf)
#pragma unroll
        for (int bf = 0; bf < 5; ++bf)
          acc[hf][bf] = __builtin_amdgcn_mfma_f32_16x16x32_bf16(A[ks & 1][hf], Bc[bf], acc[hf][bf], 0, 0, 0);
      __builtin_amdgcn_s_setprio(0);
      if (ks < 14) {
#pragma unroll
        for (int hf = 0; hf < 2; ++hf)
          A[ks & 1][hf] = *(const bf16x8*)(Wl2 + (hf << 14) + ((ks + 2) << 10));
      }
    }
    float part[5] = {0.f, 0.f, 0.f, 0.f, 0.f};
#pragma unroll
    for (int hf = 0; hf < 2; ++hf) {
      int hb = (w << 5) + (hf << 4) + (l4 << 2);
      float4 bias = *(const float4*)(b2 + (a << 9) + hb);
      float4 w3v = *(const float4*)(W3 + (a << 9) + hb);
#pragma unroll
      for (int bf = 0; bf < 5; ++bf) {
        part[bf] += fmaxf(acc[hf][bf][0] + bias.x, 0.f) * w3v.x +
                    fmaxf(acc[hf][bf][1] + bias.y, 0.f) * w3v.y +
                    fmaxf(acc[hf][bf][2] + bias.z, 0.f) * w3v.z +
                    fmaxf(acc[hf][bf][3] + bias.w, 0.f) * w3v.w;
      }
    }
#pragma unroll
    for (int bf = 0; bf < 5; ++bf) {
      float p = part[bf];
      p += __shfl_xor(p, 16);
      p += __shfl_xor(p, 32);
      if (l4 == 0) outbuf[w * TR + (bf << 4) + l15] = p;
    }
  }
  __syncthreads();
  if (tid < nrows) {
    float s = b3[a];
#pragma unroll
    for (int ww = 0; ww < 16; ++ww) s += outbuf[ww * TR + tid];
    out[perm[rowbase + tid]] = s;
  }
}

extern "C" void kernel_launch(void* const* d_in, const int* in_sizes, int n_in,
                              void* d_out, int out_size, void* d_ws, size_t ws_size,
                              hipStream_t stream) {
  const float* state = (const float*)d_in[0];
  const float* W1 = (const float*)d_in[1];
  const float* b1 = (const float*)d_in[2];
  const float* W2 = (const float*)d_in[3];
  const float* b2 = (const float*)d_in[4];
  const float* W3 = (const float*)d_in[5];
  const float* b3 = (const float*)d_in[6];
  const int* actions = (const int*)d_in[7];
  float* out = (float*)d_out;
  char* ws = (char*)d_ws;
  bf16* W1s = (bf16*)(ws + W1S_OFF);
  bf16* W2s = (bf16*)(ws + W2S_OFF);
  int* perm = (int*)(ws + PERM_OFF);
  int* meta = (int*)(ws + META_OFF);

  k_prep<<<513, 256, 0, stream>>>(W1, W2, W1s, W2s, actions, meta, perm);
  hipFuncSetAttribute((const void*)k_main, hipFuncAttributeMaxDynamicSharedMemorySize, 87040);
  k_main<<<256, 1024, 87040, stream>>>(state, b1, b2, W3, b3, W1s, W2s, perm, meta, out);
}